// Round 1
// baseline (526.201 us; speedup 1.0000x reference)
//
#include <hip/hip_runtime.h>
#include <hip/hip_bf16.h>
#include <math.h>

typedef __attribute__((ext_vector_type(8))) short bf16x8;
typedef __attribute__((ext_vector_type(4))) short short4v;
typedef __attribute__((ext_vector_type(4))) float f32x4;

#define NTOT 8192
#define DIM  1024
#define BM   128
#define BK   64
#define NCHUNK (NTOT / 64)   // 128 column chunks of 64

// round-to-nearest-even fp32 -> bf16 (inputs are finite, no NaN handling needed)
__device__ __forceinline__ unsigned short f2bf(float f) {
  union { float f; unsigned u; } v; v.f = f;
  unsigned r = v.u + 0x7FFFu + ((v.u >> 16) & 1u);
  return (unsigned short)(r >> 16);
}

// -------- exact fp32 diagonal: diag[i] = dot(src[i], trg[i]) --------
__global__ __launch_bounds__(256)
void diag_kernel(const float* __restrict__ A, const float* __restrict__ B,
                 float* __restrict__ diag) {
  const int wid  = (blockIdx.x * 256 + threadIdx.x) >> 6;   // one wave per row
  const int lane = threadIdx.x & 63;
  if (wid >= NTOT) return;
  const f32x4* a = (const f32x4*)(A + (size_t)wid * DIM);
  const f32x4* b = (const f32x4*)(B + (size_t)wid * DIM);
  float s = 0.f;
#pragma unroll
  for (int i = 0; i < DIM / 4 / 64; ++i) {
    f32x4 x = a[i * 64 + lane];
    f32x4 y = b[i * 64 + lane];
    s += x.x * y.x + x.y * y.y + x.z * y.z + x.w * y.w;
  }
#pragma unroll
  for (int off = 32; off; off >>= 1) s += __shfl_xor(s, off);
  if (lane == 0) diag[wid] = s;
}

// -------- fused bf16 GEMM tile + online row-max/sum-exp partials --------
// grid = (64 col-tiles, 64 row-tiles), 256 threads = 4 waves in 2x2.
// Each wave owns a 64x64 output subtile; writes (m, l) per row for its
// 64-col chunk to partials[row * NCHUNK + chunk].
__global__ __launch_bounds__(256, 2)
void gemm_lse(const float* __restrict__ A, const float* __restrict__ Bm,
              float2* __restrict__ partials) {
  __shared__ __align__(16) unsigned short As[BM * BK];
  __shared__ __align__(16) unsigned short Bs[BM * BK];

  const int bx = blockIdx.x;           // col tile
  const int by = blockIdx.y;           // row tile
  const int tid  = threadIdx.x;
  const int lane = tid & 63;
  const int wid  = tid >> 6;
  const int wr = wid >> 1, wc = wid & 1;

  f32x4 acc[4][4] = {};

  const size_t row0 = (size_t)by * BM;
  const size_t col0 = (size_t)bx * BM;

  // staging: 256 threads x float4 = 1024 f32 = 16 rows x 64 cols per iter
  const int sr = tid >> 4;   // row within 16-row group
  const int sc = tid & 15;   // float4 index within row

  for (int k0 = 0; k0 < DIM; k0 += BK) {
    __syncthreads();
#pragma unroll
    for (int it = 0; it < 8; ++it) {
      const int r = it * 16 + sr;
      f32x4 a = *(const f32x4*)(A  + (row0 + r) * DIM + k0 + sc * 4);
      f32x4 b = *(const f32x4*)(Bm + (col0 + r) * DIM + k0 + sc * 4);
      short4v av = { (short)f2bf(a.x), (short)f2bf(a.y), (short)f2bf(a.z), (short)f2bf(a.w) };
      short4v bv = { (short)f2bf(b.x), (short)f2bf(b.y), (short)f2bf(b.z), (short)f2bf(b.w) };
      // XOR swizzle: spread 128B-stride rows across banks (G4 fix)
      const int boff = (sc * 8) ^ ((r & 7) << 4);
      *(short4v*)((char*)As + r * 128 + boff) = av;
      *(short4v*)((char*)Bs + r * 128 + boff) = bv;
    }
    __syncthreads();

#pragma unroll
    for (int ks = 0; ks < 2; ++ks) {
      const int kb = ks * 64 + ((lane >> 4) << 4);   // byte offset of 8-elem K-slice
      bf16x8 af[4], bfr[4];
#pragma unroll
      for (int mi = 0; mi < 4; ++mi) {
        const int r = wr * 64 + mi * 16 + (lane & 15);
        af[mi] = *(const bf16x8*)((const char*)As + r * 128 + (kb ^ ((r & 7) << 4)));
      }
#pragma unroll
      for (int ni = 0; ni < 4; ++ni) {
        const int r = wc * 64 + ni * 16 + (lane & 15);
        bfr[ni] = *(const bf16x8*)((const char*)Bs + r * 128 + (kb ^ ((r & 7) << 4)));
      }
#pragma unroll
      for (int mi = 0; mi < 4; ++mi)
#pragma unroll
        for (int ni = 0; ni < 4; ++ni)
          acc[mi][ni] = __builtin_amdgcn_mfma_f32_16x16x32_bf16(af[mi], bfr[ni], acc[mi][ni], 0, 0, 0);
    }
  }

  // epilogue: per-row (max, sum-exp) over this wave's 64 cols.
  // C/D layout: col = lane&15, row = (lane>>4)*4 + reg  [m89/m91]
  const int chunk = bx * 2 + wc;
#pragma unroll
  for (int mi = 0; mi < 4; ++mi) {
#pragma unroll
    for (int j = 0; j < 4; ++j) {
      float m = acc[mi][0][j];
      m = fmaxf(m, acc[mi][1][j]);
      m = fmaxf(m, acc[mi][2][j]);
      m = fmaxf(m, acc[mi][3][j]);
#pragma unroll
      for (int off = 8; off; off >>= 1) m = fmaxf(m, __shfl_xor(m, off));
      float l = 0.f;
#pragma unroll
      for (int ni = 0; ni < 4; ++ni) l += __expf(acc[mi][ni][j] - m);
#pragma unroll
      for (int off = 8; off; off >>= 1) l += __shfl_xor(l, off);
      if ((lane & 15) == 0) {
        const int row = (int)row0 + wr * 64 + mi * 16 + ((lane >> 4) << 2) + j;
        partials[(size_t)row * NCHUNK + chunk] = make_float2(m, l);
      }
    }
  }
}

// -------- per-row combine: lse = M + log(sum l_j * exp(m_j - M)) --------
__global__ __launch_bounds__(256)
void row_lse_kernel(const float2* __restrict__ partials,
                    const float* __restrict__ diag,
                    float* __restrict__ rowval) {
  const int row  = (blockIdx.x * 256 + threadIdx.x) >> 6;   // one wave per row
  const int lane = threadIdx.x & 63;
  if (row >= NTOT) return;
  const float2 p0 = partials[(size_t)row * NCHUNK + lane];
  const float2 p1 = partials[(size_t)row * NCHUNK + 64 + lane];
  float m = fmaxf(p0.x, p1.x);
#pragma unroll
  for (int off = 32; off; off >>= 1) m = fmaxf(m, __shfl_xor(m, off));
  float l = p0.y * __expf(p0.x - m) + p1.y * __expf(p1.x - m);
#pragma unroll
  for (int off = 32; off; off >>= 1) l += __shfl_xor(l, off);
  if (lane == 0) rowval[row] = diag[row] - (m + __logf(l));
}

// -------- final scalar: out = -(sum rowval)/N + EPS --------
__global__ __launch_bounds__(256)
void final_reduce(const float* __restrict__ rowval, float* __restrict__ out) {
  __shared__ float sm[4];
  float s = 0.f;
  for (int i = threadIdx.x; i < NTOT; i += 256) s += rowval[i];
#pragma unroll
  for (int off = 32; off; off >>= 1) s += __shfl_xor(s, off);
  if ((threadIdx.x & 63) == 0) sm[threadIdx.x >> 6] = s;
  __syncthreads();
  if (threadIdx.x == 0) {
    float t = sm[0] + sm[1] + sm[2] + sm[3];
    out[0] = -(t / (float)NTOT) + 1e-9f;
  }
}

extern "C" void kernel_launch(void* const* d_in, const int* in_sizes, int n_in,
                              void* d_out, int out_size, void* d_ws, size_t ws_size,
                              hipStream_t stream) {
  const float* src = (const float*)d_in[0];
  const float* trg = (const float*)d_in[1];
  float* out = (float*)d_out;

  // workspace layout: [diag: 8192 f32][rowval: 8192 f32][pad to 64KB][partials: 8192*128 float2]
  float*  diag     = (float*)d_ws;
  float*  rowval   = diag + NTOT;
  float2* partials = (float2*)((char*)d_ws + 65536);

  diag_kernel<<<NTOT / 4, 256, 0, stream>>>(src, trg, diag);

  dim3 grid(NTOT / BM, NTOT / BM);
  gemm_lse<<<grid, 256, 0, stream>>>(src, trg, partials);

  row_lse_kernel<<<NTOT / 4, 256, 0, stream>>>(partials, diag, rowval);
  final_reduce<<<1, 256, 0, stream>>>(rowval, out);
}

// Round 2
// 185.275 us; speedup vs baseline: 2.8401x; 2.8401x over previous
//
#include <hip/hip_runtime.h>
#include <hip/hip_bf16.h>
#include <math.h>

typedef __attribute__((ext_vector_type(8))) short bf16x8;
typedef __attribute__((ext_vector_type(4))) short short4v;
typedef __attribute__((ext_vector_type(4))) float f32x4;

#define NTOT 8192
#define DIM  1024
#define BM   128
#define BK   64
#define NCHUNK (NTOT / 64)   // 128 column chunks of 64

// round-to-nearest-even fp32 -> bf16
__device__ __forceinline__ unsigned short f2bf(float f) {
  union { float f; unsigned u; } v; v.f = f;
  unsigned r = v.u + 0x7FFFu + ((v.u >> 16) & 1u);
  return (unsigned short)(r >> 16);
}

__device__ __forceinline__ void gload_lds16(const unsigned short* g, unsigned short* l) {
  __builtin_amdgcn_global_load_lds(
      (const __attribute__((address_space(1))) unsigned int*)g,
      (__attribute__((address_space(3))) unsigned int*)l,
      16, 0, 0);
}

// -------- fused: fp32 -> bf16 convert of both inputs + exact fp32 diagonal --------
// one wave per row (1024 f32 = 4 x (64 lanes x f32x4) per array)
__global__ __launch_bounds__(256)
void convert_diag(const float* __restrict__ src, const float* __restrict__ trg,
                  unsigned short* __restrict__ Abf, unsigned short* __restrict__ Bbf,
                  float* __restrict__ diag) {
  const int row  = blockIdx.x * 4 + (threadIdx.x >> 6);
  const int lane = threadIdx.x & 63;
  const f32x4* a = (const f32x4*)(src + (size_t)row * DIM);
  const f32x4* b = (const f32x4*)(trg + (size_t)row * DIM);
  float s = 0.f;
#pragma unroll
  for (int j = 0; j < 4; ++j) {
    f32x4 x = a[j * 64 + lane];
    f32x4 y = b[j * 64 + lane];
    s += x.x * y.x + x.y * y.y + x.z * y.z + x.w * y.w;
    short4v av = { (short)f2bf(x.x), (short)f2bf(x.y), (short)f2bf(x.z), (short)f2bf(x.w) };
    short4v bv = { (short)f2bf(y.x), (short)f2bf(y.y), (short)f2bf(y.z), (short)f2bf(y.w) };
    *(short4v*)(Abf + (size_t)row * DIM + (j * 64 + lane) * 4) = av;
    *(short4v*)(Bbf + (size_t)row * DIM + (j * 64 + lane) * 4) = bv;
  }
#pragma unroll
  for (int off = 32; off; off >>= 1) s += __shfl_xor(s, off);
  if (lane == 0) diag[row] = s;
}

// -------- bf16 GEMM tile (global_load_lds staging) + row-max/sum-exp partials --------
// grid = (64, 64), 256 threads = 4 waves in 2x2; each wave owns a 64x64 subtile.
// LDS: linear dest for global_load_lds; source pre-swizzled so that reads with
// byte ^= ((row&7)<<4) are bank-conflict-free (rule 21: both-sides-or-neither).
__global__ __launch_bounds__(256, 2)
void gemm_lse(const unsigned short* __restrict__ Abf, const unsigned short* __restrict__ Bbf,
              float2* __restrict__ partials) {
  __shared__ __align__(16) unsigned short As[BM * BK];
  __shared__ __align__(16) unsigned short Bs[BM * BK];

  const int bx = blockIdx.x;           // col tile
  const int by = blockIdx.y;           // row tile
  const int tid  = threadIdx.x;
  const int lane = tid & 63;
  const int wid  = tid >> 6;
  const int wr = wid >> 1, wc = wid & 1;

  f32x4 acc[4][4] = {};

  const size_t row0 = (size_t)by * BM;
  const size_t col0 = (size_t)bx * BM;

  const int lrow = lane >> 3;          // row within 8-row group
  const int lcol = lane & 7;           // 16B chunk within 128B row

  for (int k0 = 0; k0 < DIM; k0 += BK) {
    __syncthreads();
    // stage A and B tiles: per wave 4 issues x 8 rows each, 16B/lane
#pragma unroll
    for (int it = 0; it < 4; ++it) {
      const int r = wid * 32 + it * 8 + lrow;          // 0..127
      const int cchunk = lcol ^ (r & 7);               // inverse-swizzled source column
      const unsigned short* ga = Abf + (row0 + r) * DIM + k0 + cchunk * 8;
      const unsigned short* gb = Bbf + (col0 + r) * DIM + k0 + cchunk * 8;
      gload_lds16(ga, (unsigned short*)((char*)As + (wid * 32 + it * 8) * 128));
      gload_lds16(gb, (unsigned short*)((char*)Bs + (wid * 32 + it * 8) * 128));
    }
    __syncthreads();

#pragma unroll
    for (int ks = 0; ks < 2; ++ks) {
      const int kb = ks * 64 + ((lane >> 4) << 4);     // byte offset of 8-elem K-slice
      bf16x8 af[4], bfr[4];
#pragma unroll
      for (int mi = 0; mi < 4; ++mi) {
        const int r = wr * 64 + mi * 16 + (lane & 15);
        af[mi] = *(const bf16x8*)((const char*)As + r * 128 + (kb ^ ((r & 7) << 4)));
      }
#pragma unroll
      for (int ni = 0; ni < 4; ++ni) {
        const int r = wc * 64 + ni * 16 + (lane & 15);
        bfr[ni] = *(const bf16x8*)((const char*)Bs + r * 128 + (kb ^ ((r & 7) << 4)));
      }
#pragma unroll
      for (int mi = 0; mi < 4; ++mi)
#pragma unroll
        for (int ni = 0; ni < 4; ++ni)
          acc[mi][ni] = __builtin_amdgcn_mfma_f32_16x16x32_bf16(af[mi], bfr[ni], acc[mi][ni], 0, 0, 0);
    }
  }

  // epilogue: per-row (max, sum-exp) over this wave's 64 cols.
  // C/D layout: col = lane&15, row = (lane>>4)*4 + reg  [m89/m91]
  const int chunk = bx * 2 + wc;
#pragma unroll
  for (int mi = 0; mi < 4; ++mi) {
#pragma unroll
    for (int j = 0; j < 4; ++j) {
      float m = acc[mi][0][j];
      m = fmaxf(m, acc[mi][1][j]);
      m = fmaxf(m, acc[mi][2][j]);
      m = fmaxf(m, acc[mi][3][j]);
#pragma unroll
      for (int off = 8; off; off >>= 1) m = fmaxf(m, __shfl_xor(m, off));
      float l = 0.f;
#pragma unroll
      for (int ni = 0; ni < 4; ++ni) l += __expf(acc[mi][ni][j] - m);
#pragma unroll
      for (int off = 8; off; off >>= 1) l += __shfl_xor(l, off);
      if ((lane & 15) == 0) {
        const int row = (int)row0 + wr * 64 + mi * 16 + ((lane >> 4) << 2) + j;
        partials[(size_t)row * NCHUNK + chunk] = make_float2(m, l);
      }
    }
  }
}

// -------- per-row combine: lse = M + log(sum l_j * exp(m_j - M)) --------
__global__ __launch_bounds__(256)
void row_lse_kernel(const float2* __restrict__ partials,
                    const float* __restrict__ diag,
                    float* __restrict__ rowval) {
  const int row  = (blockIdx.x * 256 + threadIdx.x) >> 6;
  const int lane = threadIdx.x & 63;
  if (row >= NTOT) return;
  const float2 p0 = partials[(size_t)row * NCHUNK + lane];
  const float2 p1 = partials[(size_t)row * NCHUNK + 64 + lane];
  float m = fmaxf(p0.x, p1.x);
#pragma unroll
  for (int off = 32; off; off >>= 1) m = fmaxf(m, __shfl_xor(m, off));
  float l = p0.y * __expf(p0.x - m) + p1.y * __expf(p1.x - m);
#pragma unroll
  for (int off = 32; off; off >>= 1) l += __shfl_xor(l, off);
  if (lane == 0) rowval[row] = diag[row] - (m + __logf(l));
}

// -------- final scalar: out = -(sum rowval)/N + EPS --------
__global__ __launch_bounds__(256)
void final_reduce(const float* __restrict__ rowval, float* __restrict__ out) {
  __shared__ float sm[4];
  float s = 0.f;
  for (int i = threadIdx.x; i < NTOT; i += 256) s += rowval[i];
#pragma unroll
  for (int off = 32; off; off >>= 1) s += __shfl_xor(s, off);
  if ((threadIdx.x & 63) == 0) sm[threadIdx.x >> 6] = s;
  __syncthreads();
  if (threadIdx.x == 0) {
    float t = sm[0] + sm[1] + sm[2] + sm[3];
    out[0] = -(t / (float)NTOT) + 1e-9f;
  }
}

extern "C" void kernel_launch(void* const* d_in, const int* in_sizes, int n_in,
                              void* d_out, int out_size, void* d_ws, size_t ws_size,
                              hipStream_t stream) {
  const float* src = (const float*)d_in[0];
  const float* trg = (const float*)d_in[1];
  float* out = (float*)d_out;

  // workspace layout:
  // [Abf: 16MB][Bbf: 16MB][partials: 8MB][diag: 32KB][rowval: 32KB]  ~= 40.1 MB
  unsigned short* Abf = (unsigned short*)d_ws;
  unsigned short* Bbf = Abf + (size_t)NTOT * DIM;
  float2* partials = (float2*)((char*)d_ws + (size_t)32 * 1024 * 1024);
  float*  diag     = (float*)((char*)d_ws + (size_t)40 * 1024 * 1024);
  float*  rowval   = diag + NTOT;

  convert_diag<<<NTOT / 4, 256, 0, stream>>>(src, trg, Abf, Bbf, diag);

  dim3 grid(NTOT / BM, NTOT / BM);
  gemm_lse<<<grid, 256, 0, stream>>>(Abf, Bbf, partials);

  row_lse_kernel<<<NTOT / 4, 256, 0, stream>>>(partials, diag, rowval);
  final_reduce<<<1, 256, 0, stream>>>(rowval, out);
}

// Round 3
// 178.771 us; speedup vs baseline: 2.9434x; 1.0364x over previous
//
#include <hip/hip_runtime.h>
#include <hip/hip_bf16.h>
#include <math.h>

typedef __attribute__((ext_vector_type(8))) short bf16x8;
typedef __attribute__((ext_vector_type(4))) short short4v;
typedef __attribute__((ext_vector_type(4))) float f32x4;

#define NTOT 8192
#define DIM  1024
#define NCHUNK 128   // 8192 / 64 cols per chunk

// round-to-nearest-even fp32 -> bf16
__device__ __forceinline__ unsigned short f2bf(float f) {
  union { float f; unsigned u; } v; v.f = f;
  unsigned r = v.u + 0x7FFFu + ((v.u >> 16) & 1u);
  return (unsigned short)(r >> 16);
}

__device__ __forceinline__ void gload_lds16(const unsigned short* g, unsigned short* l) {
  __builtin_amdgcn_global_load_lds(
      (const __attribute__((address_space(1))) unsigned int*)g,
      (__attribute__((address_space(3))) unsigned int*)l,
      16, 0, 0);
}

#define SBAR() do { __builtin_amdgcn_sched_barrier(0); __builtin_amdgcn_s_barrier(); } while (0)

// one MFMA quadrant: 4 m-frags x 2 n-frags x 2 kk = 16 MFMA
#define MFMA_PH(MQ, NQ, A, B)                                                        \
  do {                                                                               \
    __builtin_amdgcn_s_setprio(1);                                                   \
    _Pragma("unroll")                                                                \
    for (int fm = 0; fm < 4; ++fm) {                                                 \
      _Pragma("unroll")                                                              \
      for (int fn = 0; fn < 2; ++fn) {                                               \
        acc[(MQ)*4+fm][(NQ)*2+fn] = __builtin_amdgcn_mfma_f32_16x16x32_bf16(         \
            A[fm][0], B[fn][0], acc[(MQ)*4+fm][(NQ)*2+fn], 0, 0, 0);                 \
        acc[(MQ)*4+fm][(NQ)*2+fn] = __builtin_amdgcn_mfma_f32_16x16x32_bf16(         \
            A[fm][1], B[fn][1], acc[(MQ)*4+fm][(NQ)*2+fn], 0, 0, 0);                 \
      }                                                                              \
    }                                                                                \
    __builtin_amdgcn_s_setprio(0);                                                   \
  } while (0)

// -------- fused: fp32 -> bf16 convert of both inputs + exact fp32 diagonal --------
__global__ __launch_bounds__(256)
void convert_diag(const float* __restrict__ src, const float* __restrict__ trg,
                  unsigned short* __restrict__ Abf, unsigned short* __restrict__ Bbf,
                  float* __restrict__ diag) {
  const int row  = blockIdx.x * 4 + (threadIdx.x >> 6);
  const int lane = threadIdx.x & 63;
  const f32x4* a = (const f32x4*)(src + (size_t)row * DIM);
  const f32x4* b = (const f32x4*)(trg + (size_t)row * DIM);
  float s = 0.f;
#pragma unroll
  for (int j = 0; j < 4; ++j) {
    f32x4 x = a[j * 64 + lane];
    f32x4 y = b[j * 64 + lane];
    s += x.x * y.x + x.y * y.y + x.z * y.z + x.w * y.w;
    short4v av = { (short)f2bf(x.x), (short)f2bf(x.y), (short)f2bf(x.z), (short)f2bf(x.w) };
    short4v bv = { (short)f2bf(y.x), (short)f2bf(y.y), (short)f2bf(y.z), (short)f2bf(y.w) };
    *(short4v*)(Abf + (size_t)row * DIM + (j * 64 + lane) * 4) = av;
    *(short4v*)(Bbf + (size_t)row * DIM + (j * 64 + lane) * 4) = bv;
  }
#pragma unroll
  for (int off = 32; off; off >>= 1) s += __shfl_xor(s, off);
  if (lane == 0) diag[row] = s;
}

// -------- 256x256 8-phase bf16 GEMM + fused row-max/sum-exp partials --------
// 512 threads = 8 waves (2 wr x 4 wc); per-wave output 128x64 = acc[8][4].
// LDS 128 KiB: As[b][h][hi][64][64], Bs[b][h][hi2][32][64]; 2 K-tile dbuf.
// A region h = rows {h*64..h*64+63} U {128+h*64..}; B region h = 32-col groups.
// Per phase: ds_read frag quadrant | stage 1 region (2x global_load_lds w16)
// | sched_barrier+s_barrier | setprio(1) 16 MFMA setprio(0) | barrier.
// vmcnt(6) only at phases 4 and 8 (3 regions = 6 loads in flight).
__global__ __launch_bounds__(512, 2)
void gemm_lse(const unsigned short* __restrict__ Abf, const unsigned short* __restrict__ Bbf,
              float2* __restrict__ partials) {
  __shared__ __align__(16) char lds[131072];
  char* As = lds;            // 64 KiB: 8 blocks of 8192 B  [(b*2+h)*2+hi]
  char* Bs = lds + 65536;    // 64 KiB: 4 regions of 16384 B [(b*2+h)], sub [hi2]*4096

  const int tid  = threadIdx.x;
  const int lane = tid & 63;
  const int wid  = tid >> 6;
  const int wr = wid >> 2, wc = wid & 3;
  const int bx = blockIdx.x, by = blockIdx.y;
  const int row0 = by * 256, col0 = bx * 256;

  // staging roles: 512 threads x 16B = 8 KB per issue; one region = 2 issues
  const int lrow = tid >> 3;                  // 0..63 (128B row within 8KB block)
  const int lchk = tid & 7;                   // dest 16B chunk
  const int schk = lchk ^ (lrow & 7);         // pre-swizzled source chunk (rule 21)

  auto stageA = [&](int b, int h, int t) {
#pragma unroll
    for (int hi = 0; hi < 2; ++hi) {
      char* dst = As + (((b * 2 + h) * 2 + hi) << 13) + lrow * 128 + lchk * 16;
      const unsigned short* srcp = Abf + (size_t)(row0 + hi * 128 + h * 64 + lrow) * DIM
                                       + t * 64 + schk * 8;
      gload_lds16(srcp, (unsigned short*)dst);
    }
  };
  auto stageB = [&](int b, int h, int t) {
#pragma unroll
    for (int j = 0; j < 2; ++j) {
      char* dst = Bs + ((b * 2 + h) << 14) + j * 8192 + lrow * 128 + lchk * 16;
      const unsigned short* srcp = Bbf + (size_t)(col0 + (2 * j + (lrow >> 5)) * 64 + h * 32 + (lrow & 31)) * DIM
                                       + t * 64 + schk * 8;
      gload_lds16(srcp, (unsigned short*)dst);
    }
  };

  // fragment read addressing (swizzled): row stride 128B, kbyte ^= (row&7)<<4
  const int arow = (lane & 15) * 128;
  const int kb0 = (((lane >> 4) * 16)     ) ^ ((lane & 7) << 4);
  const int kb1 = (((lane >> 4) * 16) + 64) ^ ((lane & 7) << 4);

  auto rdA = [&](bf16x8 (&a)[4][2], int b, int h) {
    const char* base = As + (((b * 2 + h) * 2 + wr) << 13);
#pragma unroll
    for (int f = 0; f < 4; ++f) {
      a[f][0] = *(const bf16x8*)(base + f * 2048 + arow + kb0);
      a[f][1] = *(const bf16x8*)(base + f * 2048 + arow + kb1);
    }
  };
  auto rdB = [&](bf16x8 (&bb)[2][2], int b, int h) {
    const char* base = Bs + ((b * 2 + h) << 14) + wc * 4096;
#pragma unroll
    for (int f = 0; f < 2; ++f) {
      bb[f][0] = *(const bf16x8*)(base + f * 2048 + arow + kb0);
      bb[f][1] = *(const bf16x8*)(base + f * 2048 + arow + kb1);
    }
  };

  f32x4 acc[8][4] = {};
  bf16x8 a_lo[4][2], a_hi[4][2], b_lo[2][2], b_hi[2][2];

  // prologue: stage tile0 fully (buf0) + 3 regions of tile1 (buf1); 14 loads
  stageA(0, 0, 0); stageA(0, 1, 0); stageB(0, 0, 0); stageB(0, 1, 0);
  stageA(1, 0, 1); stageB(1, 0, 1); stageB(1, 1, 1);
  asm volatile("s_waitcnt vmcnt(6)" ::: "memory");   // tile0 landed, 6 in flight
  SBAR();

  for (int i = 0; i < 8; ++i) {
    const bool last = (i == 7);
    const int t1 = 2 * i + 1, t2 = 2 * i + 2, t3 = 2 * i + 3;

    // ---- K-tile 2i from buf0 ----
    // ph1: quadrant (0,0)
    rdA(a_lo, 0, 0); rdB(b_lo, 0, 0);
    stageA(1, 1, t1);                     // 4th region of tile 2i+1 (freed prev ph7)
    SBAR();
    MFMA_PH(0, 0, a_lo, b_lo);
    SBAR();
    // ph2: quadrant (0,1)
    rdB(b_hi, 0, 1);
    if (!last) stageA(0, 0, t2);
    SBAR();
    MFMA_PH(0, 1, a_lo, b_hi);
    SBAR();
    // ph3: quadrant (1,1)
    rdA(a_hi, 0, 1);
    if (!last) stageB(0, 0, t2);
    SBAR();
    MFMA_PH(1, 1, a_hi, b_hi);
    SBAR();
    // ph4: quadrant (1,0); ensure buf1 (tile 2i+1) fully landed
    if (!last) stageB(0, 1, t2);
    SBAR();
    MFMA_PH(1, 0, a_hi, b_lo);
    if (last) { asm volatile("s_waitcnt vmcnt(0)" ::: "memory"); }
    else      { asm volatile("s_waitcnt vmcnt(6)" ::: "memory"); }
    SBAR();

    // ---- K-tile 2i+1 from buf1 ----
    // ph5
    rdA(a_lo, 1, 0); rdB(b_lo, 1, 0);
    if (!last) stageA(0, 1, t2);
    SBAR();
    MFMA_PH(0, 0, a_lo, b_lo);
    SBAR();
    // ph6
    rdB(b_hi, 1, 1);
    if (!last) stageA(1, 0, t3);
    SBAR();
    MFMA_PH(0, 1, a_lo, b_hi);
    SBAR();
    // ph7
    rdA(a_hi, 1, 1);
    if (!last) stageB(1, 0, t3);
    SBAR();
    MFMA_PH(1, 1, a_hi, b_hi);
    SBAR();
    // ph8: ensure buf0 (tile 2i+2) fully landed for next iter
    if (!last) stageB(1, 1, t3);
    SBAR();
    MFMA_PH(1, 0, a_hi, b_lo);
    if (!last) { asm volatile("s_waitcnt vmcnt(6)" ::: "memory"); }
    SBAR();
  }

  // epilogue: per-row (max, sum-exp) over this wave's 64 cols.
  // C/D layout: col = lane&15, row = (lane>>4)*4 + j  [m89/m91]
  const int rbase  = row0 + wr * 128 + ((lane >> 4) << 2);
  const int cchunk = bx * 4 + wc;
#pragma unroll
  for (int mi = 0; mi < 8; ++mi) {
#pragma unroll
    for (int j = 0; j < 4; ++j) {
      float m = fmaxf(fmaxf(acc[mi][0][j], acc[mi][1][j]),
                      fmaxf(acc[mi][2][j], acc[mi][3][j]));
#pragma unroll
      for (int off = 8; off; off >>= 1) m = fmaxf(m, __shfl_xor(m, off));
      float l = 0.f;
#pragma unroll
      for (int ni = 0; ni < 4; ++ni) l += __expf(acc[mi][ni][j] - m);
#pragma unroll
      for (int off = 8; off; off >>= 1) l += __shfl_xor(l, off);
      if ((lane & 15) == 0)
        partials[(size_t)(rbase + mi * 16 + j) * NCHUNK + cchunk] = make_float2(m, l);
    }
  }
}

// -------- per-row combine: lse = M + log(sum l_j * exp(m_j - M)) --------
__global__ __launch_bounds__(256)
void row_lse_kernel(const float2* __restrict__ partials,
                    const float* __restrict__ diag,
                    float* __restrict__ rowval) {
  const int row  = (blockIdx.x * 256 + threadIdx.x) >> 6;
  const int lane = threadIdx.x & 63;
  if (row >= NTOT) return;
  const float2 p0 = partials[(size_t)row * NCHUNK + lane];
  const float2 p1 = partials[(size_t)row * NCHUNK + 64 + lane];
  float m = fmaxf(p0.x, p1.x);
#pragma unroll
  for (int off = 32; off; off >>= 1) m = fmaxf(m, __shfl_xor(m, off));
  float l = p0.y * __expf(p0.x - m) + p1.y * __expf(p1.x - m);
#pragma unroll
  for (int off = 32; off; off >>= 1) l += __shfl_xor(l, off);
  if (lane == 0) rowval[row] = diag[row] - (m + __logf(l));
}

// -------- final scalar: out = -(sum rowval)/N + EPS --------
__global__ __launch_bounds__(256)
void final_reduce(const float* __restrict__ rowval, float* __restrict__ out) {
  __shared__ float sm[4];
  float s = 0.f;
  for (int i = threadIdx.x; i < NTOT; i += 256) s += rowval[i];
#pragma unroll
  for (int off = 32; off; off >>= 1) s += __shfl_xor(s, off);
  if ((threadIdx.x & 63) == 0) sm[threadIdx.x >> 6] = s;
  __syncthreads();
  if (threadIdx.x == 0) {
    float t = sm[0] + sm[1] + sm[2] + sm[3];
    out[0] = -(t / (float)NTOT) + 1e-9f;
  }
}

extern "C" void kernel_launch(void* const* d_in, const int* in_sizes, int n_in,
                              void* d_out, int out_size, void* d_ws, size_t ws_size,
                              hipStream_t stream) {
  const float* src = (const float*)d_in[0];
  const float* trg = (const float*)d_in[1];
  float* out = (float*)d_out;

  // workspace: [Abf 16MB][Bbf 16MB][partials 8MB][diag 32KB][rowval 32KB]
  unsigned short* Abf = (unsigned short*)d_ws;
  unsigned short* Bbf = Abf + (size_t)NTOT * DIM;
  float2* partials = (float2*)((char*)d_ws + (size_t)32 * 1024 * 1024);
  float*  diag     = (float*)((char*)d_ws + (size_t)40 * 1024 * 1024);
  float*  rowval   = diag + NTOT;

  convert_diag<<<NTOT / 4, 256, 0, stream>>>(src, trg, Abf, Bbf, diag);

  dim3 grid(NTOT / 256, NTOT / 256);
  gemm_lse<<<grid, 512, 0, stream>>>(Abf, Bbf, partials);

  row_lse_kernel<<<NTOT / 4, 256, 0, stream>>>(partials, diag, rowval);
  final_reduce<<<1, 256, 0, stream>>>(rowval, out);
}